// Round 17
// baseline (112.564 us; speedup 1.0000x reference)
//
#include <hip/hip_runtime.h>
#include <math.h>

#define B_ 8
#define C_ 64
#define H_ 128
#define W_ 128
#define O_ 64
#define HW (H_*W_)

typedef float f32x4 __attribute__((ext_vector_type(4)));
typedef float f32x2 __attribute__((ext_vector_type(2)));
typedef short s16x8 __attribute__((ext_vector_type(8)));

// ws layout (float offsets)
#define XT_BUF   0              // NHWC bf16 x: 8*16384*64 us = 4194304 f
#define WBFA_BUF 4194304        // conv B-frags: 18432 us = 9216 f
#define WBFB_BUF 4203520        // deform B-frags: 36864 us = 18432 f

__device__ __forceinline__ unsigned short f2bf(float f) {
    union { float f; unsigned u; } v; v.f = f;
    unsigned r = (v.u + 0x7FFFu + ((v.u >> 16) & 1u)) >> 16;  // RNE
    return (unsigned short)r;
}
__device__ __forceinline__ unsigned cvt_pk_bf16(float lo, float hi) {
    unsigned r;
    asm("v_cvt_pk_bf16_f32 %0, %1, %2" : "=v"(r) : "v"(lo), "v"(hi));
    return r;
}
// u32 reg i of an s16x8 holds bf16 channels (2i) in low 16 and (2i+1) in high 16.
__device__ __forceinline__ f32x2 bfpair(s16x8 v, int i) {
    union { s16x8 s; unsigned u[4]; } c; c.s = v;
    unsigned r = c.u[i];
    union { unsigned u; float f; } lo, hi;
    lo.u = r << 16;
    hi.u = r & 0xFFFF0000u;
    f32x2 out; out.x = lo.f; out.y = hi.f;
    return out;
}
// async global->LDS, 16B per lane: LDS dst = wave-uniform base + lane*16.
__device__ __forceinline__ void gload_lds16(const void* g, void* l) {
    __builtin_amdgcn_global_load_lds(
        (const __attribute__((address_space(1))) unsigned int*)g,
        (__attribute__((address_space(3))) unsigned int*)l, 16, 0, 0);
}

// B-fragments (bf16) for mfma_f32_16x16x32_bf16:
//  B[k=c][n=oc], lane l holds c = ks*32 + (l>>4)*8 + j, oc = nt*16 + (l&15).
__global__ void prep_weights(const float* __restrict__ offw,
                             const float* __restrict__ modw,
                             const float* __restrict__ w,
                             float* __restrict__ ws) {
    int t = blockIdx.x * 256 + threadIdx.x;
    unsigned short* wbfA = (unsigned short*)(ws + WBFA_BUF);
    unsigned short* wbfB = (unsigned short*)(ws + WBFB_BUF);
    if (t < 18432) {
        int j = t & 7, lane = (t >> 3) & 63, nt = (t >> 9) & 1, ks = (t >> 10) & 1, tap = t >> 11;
        int c = ks * 32 + ((lane >> 4) & 3) * 8 + j;
        int oc = nt * 16 + (lane & 15);
        float v = 0.f;
        if (oc < 18)      v = offw[oc * (C_ * 9) + c * 9 + tap];
        else if (oc < 27) v = modw[(oc - 18) * (C_ * 9) + c * 9 + tap];
        wbfA[t] = f2bf(v);
    } else {
        int t2 = t - 18432;
        if (t2 < 36864) {
            int j = t2 & 7, lane = (t2 >> 3) & 63, nt = (t2 >> 9) & 3, ks = (t2 >> 11) & 1, tap = t2 >> 12;
            int c = ks * 32 + ((lane >> 4) & 3) * 8 + j;
            int o = nt * 16 + (lane & 15);
            wbfB[t2] = f2bf(w[o * (C_ * 9) + c * 9 + tap]);
        }
    }
}

// x NCHW fp32 -> x_t NHWC bf16 (rows of 64 ch = 128B). NT reads (read-once).
// Grid dim3(HW/64, B_) = (256, 8)  -- proven rounds 9-16, do not change.
__global__ __launch_bounds__(256) void transpose_x(const float* __restrict__ x,
                                                   float* __restrict__ ws) {
    __shared__ float lds[64 * 65];
    int b = blockIdx.x & 7;
    int chunk = (blockIdx.y << 5) | (blockIdx.x >> 3);   // 0..255
    int p0 = chunk * 64;
    int t = threadIdx.x;
    int pl = t & 63;
    const float* xb = x + (size_t)b * C_ * HW + p0;
#pragma unroll
    for (int i = 0; i < 16; i++) {
        int c = (t >> 6) + i * 4;
        lds[c * 65 + pl] = __builtin_nontemporal_load(&xb[(size_t)c * HW + pl]);
    }
    __syncthreads();
    unsigned short* xo = (unsigned short*)(ws + XT_BUF) + ((size_t)b * HW + p0) * 64;
#pragma unroll
    for (int pass = 0; pass < 2; pass++) {
        int p = (t >> 3) + pass * 32;
        int c0 = (t & 7) * 8;
        union { unsigned short u[8]; s16x8 v; } pk;
#pragma unroll
        for (int j = 0; j < 8; j++) pk.u[j] = f2bf(lds[(c0 + j) * 65 + p]);
        *(s16x8*)(xo + (size_t)p * 64 + c0) = pk.v;
    }
}

// ---- FUSED conv(27ch)+deform, 1024-thr blocks, 16x16 PIXEL TILES ----
// Identical bodies to round 16 (passing). Only the block->pixel mapping
// changes: block = 16x16 tile (wave wv = tile row), so the per-tap gather
// halo (18x18 px ~ 41KB) largely fits the CU's 32KB L1 (1 block/CU due to
// 99KB LDS), converting repeated L2 round-trips into L1 hits.
__global__ __launch_bounds__(1024) void fused(const float* __restrict__ ws,
                                              const float* __restrict__ offb,
                                              const float* __restrict__ modb,
                                              float* __restrict__ out) {
    __shared__ s16x8 bflv[4608];         // 73728 B: [tap][ks][nt][lane]
    __shared__ float offL[16][18][16];   // 18432 B: [wave][oc][px]
    __shared__ float mskL[16][9][16];    //  9216 B
    int t = threadIdx.x;
    int wv = t >> 6, l = t & 63;
    int b = blockIdx.x & 7;
    int tile = (blockIdx.y << 3) | (blockIdx.x >> 3);    // 0..63
    int ty = tile >> 3, tx = tile & 7;                   // 8x8 tiles of 16x16
    int pw = (ty * 16 + wv) * W_ + tx * 16;              // wave = tile row wv
    int y = pw >> 7, x0 = pw & 127;
    int pl = l & 15, csub = l >> 4;

    const unsigned short* xtb = (const unsigned short*)(ws + XT_BUF) + (size_t)b * HW * 64;
    const s16x8* wbfA = (const s16x8*)(ws + WBFA_BUF);

    // stage deform B-frags (72 chunks of 1KB) across 16 waves
    {
        const char* wsrc = (const char*)(ws + WBFB_BUF);
        char* dstb = (char*)bflv;
#pragma unroll
        for (int i = 0; i < 4; i++) {
            int ch = wv * 4 + i;
            gload_lds16(wsrc + ch * 1024 + l * 16, dstb + ch * 1024);
        }
        if (wv < 8) {
            int ch = 64 + wv;
            gload_lds16(wsrc + ch * 1024 + l * 16, dstb + ch * 1024);
        }
    }

    // ================= phase 1: conv (verbatim body) =================
    {
        int oc0 = pl, oc1 = 16 + pl;
        float bi0 = offb[oc0];
        float bi1 = (oc1 < 18) ? offb[oc1] : (oc1 < 27 ? modb[oc1 - 18] : 0.f);
        f32x4 acc0 = {bi0, bi0, bi0, bi0};
        f32x4 acc1 = {bi1, bi1, bi1, bi1};
        const s16x8 zf = {0, 0, 0, 0, 0, 0, 0, 0};

        for (int tap = 0; tap < 9; tap++) {
            int ys = y + tap / 3 - 1;
            int xs = x0 + pl + tap % 3 - 1;
            bool vld = ((unsigned)ys < (unsigned)H_) && ((unsigned)xs < (unsigned)W_);
            int yc = min(max(ys, 0), H_ - 1);
            int xc = min(max(xs, 0), W_ - 1);
            const unsigned short* rp = xtb + (size_t)(yc * W_ + xc) * 64 + csub * 8;
            s16x8 a0 = *(const s16x8*)rp;
            s16x8 a1 = *(const s16x8*)(rp + 32);
            a0 = vld ? a0 : zf;
            a1 = vld ? a1 : zf;
            s16x8 b00 = wbfA[((tap * 2 + 0) * 2 + 0) * 64 + l];
            s16x8 b01 = wbfA[((tap * 2 + 0) * 2 + 1) * 64 + l];
            s16x8 b10 = wbfA[((tap * 2 + 1) * 2 + 0) * 64 + l];
            s16x8 b11 = wbfA[((tap * 2 + 1) * 2 + 1) * 64 + l];
            acc0 = __builtin_amdgcn_mfma_f32_16x16x32_bf16(a0, b00, acc0, 0, 0, 0);
            acc1 = __builtin_amdgcn_mfma_f32_16x16x32_bf16(a0, b01, acc1, 0, 0, 0);
            acc0 = __builtin_amdgcn_mfma_f32_16x16x32_bf16(a1, b10, acc0, 0, 0, 0);
            acc1 = __builtin_amdgcn_mfma_f32_16x16x32_bf16(a1, b11, acc1, 0, 0, 0);
        }

        // epilogue -> LDS (D row = pixel csub*4+j, col = oc)
#pragma unroll
        for (int j = 0; j < 4; j++)
            offL[wv][oc0][csub * 4 + j] = fminf(fmaxf(acc0[j], -32.f), 32.f);
        if (oc1 < 18) {
#pragma unroll
            for (int j = 0; j < 4; j++)
                offL[wv][oc1][csub * 4 + j] = fminf(fmaxf(acc1[j], -32.f), 32.f);
        } else if (oc1 < 27) {
#pragma unroll
            for (int j = 0; j < 4; j++)
                mskL[wv][oc1 - 18][csub * 4 + j] = 2.f / (1.f + __expf(-acc1[j]));
        }
    }
    __syncthreads();   // publishes offL/mskL AND drains the B-frag staging

    // ================= phase 2: deform (verbatim body, LDS weights) ==========
    int xx = x0 + pl;
    const unsigned short* xtb2 = xtb + csub * 8;

    float dyv[9], dxv[9], mmv[9];
#pragma unroll
    for (int tap = 0; tap < 9; tap++) {
        dyv[tap] = offL[wv][2 * tap][pl];
        dxv[tap] = offL[wv][2 * tap + 1][pl];
        mmv[tap] = mskL[wv][tap][pl];
    }

    f32x4 acc[4];
#pragma unroll
    for (int nt = 0; nt < 4; nt++) acc[nt] = (f32x4)0.f;

#pragma unroll
    for (int tap = 0; tap < 9; tap++) {
        float py = (float)(y + tap / 3 - 1) + dyv[tap];
        float px = (float)(xx + tap % 3 - 1) + dxv[tap];
        float mm = mmv[tap];
        float fy = floorf(py), fx = floorf(px);
        int y0 = (int)fy, xq = (int)fx;
        float wy = py - fy, wx = px - fx;
        bool vy0 = (unsigned)y0 < (unsigned)H_;
        bool vy1 = (unsigned)(y0 + 1) < (unsigned)H_;
        bool vx0 = (unsigned)xq < (unsigned)W_;
        bool vx1 = (unsigned)(xq + 1) < (unsigned)W_;
        int yc0 = min(max(y0, 0), H_ - 1), yc1 = min(max(y0 + 1, 0), H_ - 1);
        int xc0 = min(max(xq, 0), W_ - 1), xc1 = min(max(xq + 1, 0), W_ - 1);
        float e0 = (1.f - wy) * (1.f - wx) * mm * ((vy0 && vx0) ? 1.f : 0.f);
        float e1 = (1.f - wy) * wx         * mm * ((vy0 && vx1) ? 1.f : 0.f);
        float e2 = wy * (1.f - wx)         * mm * ((vy1 && vx0) ? 1.f : 0.f);
        float e3 = wy * wx                 * mm * ((vy1 && vx1) ? 1.f : 0.f);

        const unsigned short* p00 = xtb2 + (size_t)(yc0 * W_ + xc0) * 64;
        const unsigned short* p01 = xtb2 + (size_t)(yc0 * W_ + xc1) * 64;
        const unsigned short* p10 = xtb2 + (size_t)(yc1 * W_ + xc0) * 64;
        const unsigned short* p11 = xtb2 + (size_t)(yc1 * W_ + xc1) * 64;
        s16x8 g00a = *(const s16x8*)p00, g00b = *(const s16x8*)(p00 + 32);
        s16x8 g01a = *(const s16x8*)p01, g01b = *(const s16x8*)(p01 + 32);
        s16x8 g10a = *(const s16x8*)p10, g10b = *(const s16x8*)(p10 + 32);
        s16x8 g11a = *(const s16x8*)p11, g11b = *(const s16x8*)(p11 + 32);

        f32x2 e0v = {e0, e0}, e1v = {e1, e1}, e2v = {e2, e2}, e3v = {e3, e3};
        union { unsigned u[4]; s16x8 v; } A0, A1;
#pragma unroll
        for (int q = 0; q < 4; q++) {
            f32x2 va = e0v * bfpair(g00a, q) + e1v * bfpair(g01a, q)
                     + e2v * bfpair(g10a, q) + e3v * bfpair(g11a, q);
            A0.u[q] = cvt_pk_bf16(va.x, va.y);
            f32x2 vb = e0v * bfpair(g00b, q) + e1v * bfpair(g01b, q)
                     + e2v * bfpair(g10b, q) + e3v * bfpair(g11b, q);
            A1.u[q] = cvt_pk_bf16(vb.x, vb.y);
        }
#pragma unroll
        for (int nt = 0; nt < 4; nt++) {
            s16x8 bf0 = bflv[((tap * 2 + 0) * 4 + nt) * 64 + l];   // ds_read_b128
            s16x8 bf1 = bflv[((tap * 2 + 1) * 4 + nt) * 64 + l];
            acc[nt] = __builtin_amdgcn_mfma_f32_16x16x32_bf16(A0.v, bf0, acc[nt], 0, 0, 0);
            acc[nt] = __builtin_amdgcn_mfma_f32_16x16x32_bf16(A1.v, bf1, acc[nt], 0, 0, 0);
        }
    }

    float* ob = out + (size_t)b * O_ * HW;
    int gp0 = pw + csub * 4;
#pragma unroll
    for (int nt = 0; nt < 4; nt++) {
        int oc = nt * 16 + pl;
        *(f32x4*)(ob + (size_t)oc * HW + gp0) = acc[nt];
    }
}

extern "C" void kernel_launch(void* const* d_in, const int* in_sizes, int n_in,
                              void* d_out, int out_size, void* d_ws, size_t ws_size,
                              hipStream_t stream) {
    const float* x    = (const float*)d_in[0];
    const float* offw = (const float*)d_in[1];
    const float* offb = (const float*)d_in[2];
    const float* modw = (const float*)d_in[3];
    const float* modb = (const float*)d_in[4];
    const float* w    = (const float*)d_in[5];
    float* out = (float*)d_out;
    float* ws  = (float*)d_ws;

    prep_weights<<<dim3(216), dim3(256), 0, stream>>>(offw, modw, w, ws);
    transpose_x<<<dim3(HW / 64, B_), dim3(256), 0, stream>>>(x, ws);
    fused<<<dim3(64, 8), dim3(1024), 0, stream>>>(ws, offb, modb, out);
}

// Round 19
// 89.861 us; speedup vs baseline: 1.2527x; 1.2527x over previous
//
#include <hip/hip_runtime.h>
#include <math.h>

#define B_ 8
#define C_ 64
#define H_ 128
#define W_ 128
#define O_ 64
#define HW (H_*W_)

typedef float f32x4 __attribute__((ext_vector_type(4)));
typedef float f32x2 __attribute__((ext_vector_type(2)));
typedef short s16x8 __attribute__((ext_vector_type(8)));

// ws layout (float offsets)
#define XT_BUF   0              // NHWC bf16 x: 8*16384*64 us = 4194304 f
#define WBFA_BUF 4194304        // conv B-frags: 18432 us = 9216 f
#define WBFB_BUF 4203520        // deform B-frags: 36864 us = 18432 f

__device__ __forceinline__ unsigned short f2bf(float f) {
    union { float f; unsigned u; } v; v.f = f;
    unsigned r = (v.u + 0x7FFFu + ((v.u >> 16) & 1u)) >> 16;  // RNE
    return (unsigned short)r;
}
__device__ __forceinline__ unsigned cvt_pk_bf16(float lo, float hi) {
    unsigned r;
    asm("v_cvt_pk_bf16_f32 %0, %1, %2" : "=v"(r) : "v"(lo), "v"(hi));
    return r;
}
// u32 reg i of an s16x8 holds bf16 channels (2i) in low 16 and (2i+1) in high 16.
__device__ __forceinline__ f32x2 bfpair(s16x8 v, int i) {
    union { s16x8 s; unsigned u[4]; } c; c.s = v;
    unsigned r = c.u[i];
    union { unsigned u; float f; } lo, hi;
    lo.u = r << 16;
    hi.u = r & 0xFFFF0000u;
    f32x2 out; out.x = lo.f; out.y = hi.f;
    return out;
}

// B-fragments (bf16) for mfma_f32_16x16x32_bf16:
//  B[k=c][n=oc], lane l holds c = ks*32 + (l>>4)*8 + j, oc = nt*16 + (l&15).
__global__ void prep_weights(const float* __restrict__ offw,
                             const float* __restrict__ modw,
                             const float* __restrict__ w,
                             float* __restrict__ ws) {
    int t = blockIdx.x * 256 + threadIdx.x;
    unsigned short* wbfA = (unsigned short*)(ws + WBFA_BUF);
    unsigned short* wbfB = (unsigned short*)(ws + WBFB_BUF);
    if (t < 18432) {
        int j = t & 7, lane = (t >> 3) & 63, nt = (t >> 9) & 1, ks = (t >> 10) & 1, tap = t >> 11;
        int c = ks * 32 + ((lane >> 4) & 3) * 8 + j;
        int oc = nt * 16 + (lane & 15);
        float v = 0.f;
        if (oc < 18)      v = offw[oc * (C_ * 9) + c * 9 + tap];
        else if (oc < 27) v = modw[(oc - 18) * (C_ * 9) + c * 9 + tap];
        wbfA[t] = f2bf(v);
    } else {
        int t2 = t - 18432;
        if (t2 < 36864) {
            int j = t2 & 7, lane = (t2 >> 3) & 63, nt = (t2 >> 9) & 3, ks = (t2 >> 11) & 1, tap = t2 >> 12;
            int c = ks * 32 + ((lane >> 4) & 3) * 8 + j;
            int o = nt * 16 + (lane & 15);
            wbfB[t2] = f2bf(w[o * (C_ * 9) + c * 9 + tap]);
        }
    }
}

// x NCHW fp32 -> x_t NHWC bf16 (rows of 64 ch = 128B). NT reads (read-once).
__global__ __launch_bounds__(256) void transpose_x(const float* __restrict__ x,
                                                   float* __restrict__ ws) {
    __shared__ float lds[64 * 65];
    int b = blockIdx.x & 7;
    int chunk = (blockIdx.y << 5) | (blockIdx.x >> 3);   // 0..255
    int p0 = chunk * 64;
    int t = threadIdx.x;
    int pl = t & 63;
    const float* xb = x + (size_t)b * C_ * HW + p0;
#pragma unroll
    for (int i = 0; i < 16; i++) {
        int c = (t >> 6) + i * 4;
        lds[c * 65 + pl] = __builtin_nontemporal_load(&xb[(size_t)c * HW + pl]);
    }
    __syncthreads();
    unsigned short* xo = (unsigned short*)(ws + XT_BUF) + ((size_t)b * HW + p0) * 64;
#pragma unroll
    for (int pass = 0; pass < 2; pass++) {
        int p = (t >> 3) + pass * 32;
        int c0 = (t & 7) * 8;
        union { unsigned short u[8]; s16x8 v; } pk;
#pragma unroll
        for (int j = 0; j < 8; j++) pk.u[j] = f2bf(lds[(c0 + j) * 65 + p]);
        *(s16x8*)(xo + (size_t)p * 64 + c0) = pk.v;
    }
}

// ---- FUSED conv+deform: phase-2 gathers from a 27x27 LDS x-tile ----
// Conv phase: verbatim round-16 (global reads). Phase 2: UNCONDITIONAL
// swizzled ds_read_b128 at clamped tile coords (staging replicates the image
// clamp, so image-border samples stay in-tile); rare predicated global fixup
// for far-offset lanes (|off| > halo 5, ~2%). Weights from global (coalesced).
// LDS: 93312 (tile) + 18432 + 9216 = 120960 B -> 1 block/CU, 16 waves.
__global__ __launch_bounds__(1024) void fused(const float* __restrict__ ws,
                                              const float* __restrict__ offb,
                                              const float* __restrict__ modb,
                                              float* __restrict__ out) {
    __shared__ s16x8 xtile_v[5832];      // 93312 B: 729 px * 128B, swizzled
    __shared__ float offL[16][18][16];   // [wave][oc][px]
    __shared__ float mskL[16][9][16];
    char* xtile = (char*)xtile_v;
    int t = threadIdx.x;
    int wv = t >> 6, l = t & 63;
    int b = blockIdx.x & 7;
    int tile = (blockIdx.y << 3) | (blockIdx.x >> 3);    // 0..63
    int ty = tile >> 3, tx = tile & 7;
    int t0y = ty * 16, t0x = tx * 16;
    int y = t0y + wv, x0 = t0x;
    int pw = y * W_ + x0;
    int pl = l & 15, csub = l >> 4;

    const unsigned short* xtb = (const unsigned short*)(ws + XT_BUF) + (size_t)b * HW * 64;
    const s16x8* wbfA = (const s16x8*)(ws + WBFA_BUF);
    const s16x8* wbfB = (const s16x8*)(ws + WBFB_BUF);

    // stage x-tile: 27x27 px * 8 chunks of 16B, XOR-swizzled (chunk ^= p&7)
#pragma unroll
    for (int k = 0; k < 6; k++) {
        int i = t + k * 1024;
        if (i < 5832) {
            int p = i >> 3, w8 = i & 7;
            int r = p / 27, cc = p - r * 27;
            int gr = min(max(t0y - 5 + r, 0), H_ - 1);
            int gc = min(max(t0x - 5 + cc, 0), W_ - 1);
            s16x8 v = *(const s16x8*)(xtb + (size_t)((gr << 7) + gc) * 64 + (w8 << 3));
            *(s16x8*)(xtile + p * 128 + ((w8 ^ (p & 7)) << 4)) = v;
        }
    }

    // ================= phase 1: conv (verbatim round-16 body) ================
    {
        int oc0 = pl, oc1 = 16 + pl;
        float bi0 = offb[oc0];
        float bi1 = (oc1 < 18) ? offb[oc1] : (oc1 < 27 ? modb[oc1 - 18] : 0.f);
        f32x4 acc0 = {bi0, bi0, bi0, bi0};
        f32x4 acc1 = {bi1, bi1, bi1, bi1};
        const s16x8 zf = {0, 0, 0, 0, 0, 0, 0, 0};

        for (int tap = 0; tap < 9; tap++) {
            int ys = y + tap / 3 - 1;
            int xs = x0 + pl + tap % 3 - 1;
            bool vld = ((unsigned)ys < (unsigned)H_) && ((unsigned)xs < (unsigned)W_);
            int yc = min(max(ys, 0), H_ - 1);
            int xc = min(max(xs, 0), W_ - 1);
            const unsigned short* rp = xtb + (size_t)(yc * W_ + xc) * 64 + csub * 8;
            s16x8 a0 = *(const s16x8*)rp;
            s16x8 a1 = *(const s16x8*)(rp + 32);
            a0 = vld ? a0 : zf;
            a1 = vld ? a1 : zf;
            s16x8 b00 = wbfA[((tap * 2 + 0) * 2 + 0) * 64 + l];
            s16x8 b01 = wbfA[((tap * 2 + 0) * 2 + 1) * 64 + l];
            s16x8 b10 = wbfA[((tap * 2 + 1) * 2 + 0) * 64 + l];
            s16x8 b11 = wbfA[((tap * 2 + 1) * 2 + 1) * 64 + l];
            acc0 = __builtin_amdgcn_mfma_f32_16x16x32_bf16(a0, b00, acc0, 0, 0, 0);
            acc1 = __builtin_amdgcn_mfma_f32_16x16x32_bf16(a0, b01, acc1, 0, 0, 0);
            acc0 = __builtin_amdgcn_mfma_f32_16x16x32_bf16(a1, b10, acc0, 0, 0, 0);
            acc1 = __builtin_amdgcn_mfma_f32_16x16x32_bf16(a1, b11, acc1, 0, 0, 0);
        }

        // epilogue -> LDS (D row = pixel csub*4+j, col = oc)
#pragma unroll
        for (int j = 0; j < 4; j++)
            offL[wv][oc0][csub * 4 + j] = fminf(fmaxf(acc0[j], -32.f), 32.f);
        if (oc1 < 18) {
#pragma unroll
            for (int j = 0; j < 4; j++)
                offL[wv][oc1][csub * 4 + j] = fminf(fmaxf(acc1[j], -32.f), 32.f);
        } else if (oc1 < 27) {
#pragma unroll
            for (int j = 0; j < 4; j++)
                mskL[wv][oc1 - 18][csub * 4 + j] = 2.f / (1.f + __expf(-acc1[j]));
        }
    }
    __syncthreads();   // publishes offL/mskL AND x-tile (barrier drains all)

    // ================= phase 2: deform, gathers from LDS tile ================
    int xx = x0 + pl;
    const unsigned short* xtb2 = xtb + csub * 8;

    float dyv[9], dxv[9], mmv[9];
#pragma unroll
    for (int tap = 0; tap < 9; tap++) {
        dyv[tap] = offL[wv][2 * tap][pl];
        dxv[tap] = offL[wv][2 * tap + 1][pl];
        mmv[tap] = mskL[wv][tap][pl];
    }

    f32x4 acc[4];
#pragma unroll
    for (int nt = 0; nt < 4; nt++) acc[nt] = (f32x4)0.f;

#pragma unroll
    for (int tap = 0; tap < 9; tap++) {
        float py = (float)(y + tap / 3 - 1) + dyv[tap];
        float px = (float)(xx + tap % 3 - 1) + dxv[tap];
        float mm = mmv[tap];
        float fy = floorf(py), fx = floorf(px);
        int y0 = (int)fy, xq = (int)fx;
        float wy = py - fy, wx = px - fx;
        bool vy0 = (unsigned)y0 < (unsigned)H_;
        bool vy1 = (unsigned)(y0 + 1) < (unsigned)H_;
        bool vx0 = (unsigned)xq < (unsigned)W_;
        bool vx1 = (unsigned)(xq + 1) < (unsigned)W_;
        int yc0 = min(max(y0, 0), H_ - 1), yc1 = min(max(y0 + 1, 0), H_ - 1);
        int xc0 = min(max(xq, 0), W_ - 1), xc1 = min(max(xq + 1, 0), W_ - 1);
        float e0 = (1.f - wy) * (1.f - wx) * mm * ((vy0 && vx0) ? 1.f : 0.f);
        float e1 = (1.f - wy) * wx         * mm * ((vy0 && vx1) ? 1.f : 0.f);
        float e2 = wy * (1.f - wx)         * mm * ((vy1 && vx0) ? 1.f : 0.f);
        float e3 = wy * wx                 * mm * ((vy1 && vx1) ? 1.f : 0.f);

        // tile coords (clamped for the unconditional LDS read; identity when
        // in-tile, and image-border clamping is replicated by the staging)
        int sy0 = yc0 - t0y + 5, sy1 = yc1 - t0y + 5;
        int sx0 = xc0 - t0x + 5, sx1 = xc1 - t0x + 5;
        bool inb = ((unsigned)sy0 < 27u) && ((unsigned)sy1 < 27u) &&
                   ((unsigned)sx0 < 27u) && ((unsigned)sx1 < 27u);
        int cy0 = min(max(sy0, 0), 26), cy1 = min(max(sy1, 0), 26);
        int cx0 = min(max(sx0, 0), 26), cx1 = min(max(sx1, 0), 26);
        int q00 = cy0 * 27 + cx0, q01 = cy0 * 27 + cx1;
        int q10 = cy1 * 27 + cx0, q11 = cy1 * 27 + cx1;

        s16x8 g00a = *(const s16x8*)(xtile + q00 * 128 + ((csub ^ (q00 & 7)) << 4));
        s16x8 g00b = *(const s16x8*)(xtile + q00 * 128 + (((4 + csub) ^ (q00 & 7)) << 4));
        s16x8 g01a = *(const s16x8*)(xtile + q01 * 128 + ((csub ^ (q01 & 7)) << 4));
        s16x8 g01b = *(const s16x8*)(xtile + q01 * 128 + (((4 + csub) ^ (q01 & 7)) << 4));
        s16x8 g10a = *(const s16x8*)(xtile + q10 * 128 + ((csub ^ (q10 & 7)) << 4));
        s16x8 g10b = *(const s16x8*)(xtile + q10 * 128 + (((4 + csub) ^ (q10 & 7)) << 4));
        s16x8 g11a = *(const s16x8*)(xtile + q11 * 128 + ((csub ^ (q11 & 7)) << 4));
        s16x8 g11b = *(const s16x8*)(xtile + q11 * 128 + (((4 + csub) ^ (q11 & 7)) << 4));

        if (!inb) {   // rare per-lane fixup: far offsets gather from global
            const unsigned short* p00 = xtb2 + (size_t)(yc0 * W_ + xc0) * 64;
            const unsigned short* p01 = xtb2 + (size_t)(yc0 * W_ + xc1) * 64;
            const unsigned short* p10 = xtb2 + (size_t)(yc1 * W_ + xc0) * 64;
            const unsigned short* p11 = xtb2 + (size_t)(yc1 * W_ + xc1) * 64;
            g00a = *(const s16x8*)p00; g00b = *(const s16x8*)(p00 + 32);
            g01a = *(const s16x8*)p01; g01b = *(const s16x8*)(p01 + 32);
            g10a = *(const s16x8*)p10; g10b = *(const s16x8*)(p10 + 32);
            g11a = *(const s16x8*)p11; g11b = *(const s16x8*)(p11 + 32);
        }

        f32x2 e0v = {e0, e0}, e1v = {e1, e1}, e2v = {e2, e2}, e3v = {e3, e3};
        union { unsigned u[4]; s16x8 v; } A0, A1;
#pragma unroll
        for (int q = 0; q < 4; q++) {
            f32x2 va = e0v * bfpair(g00a, q) + e1v * bfpair(g01a, q)
                     + e2v * bfpair(g10a, q) + e3v * bfpair(g11a, q);
            A0.u[q] = cvt_pk_bf16(va.x, va.y);
            f32x2 vb = e0v * bfpair(g00b, q) + e1v * bfpair(g01b, q)
                     + e2v * bfpair(g10b, q) + e3v * bfpair(g11b, q);
            A1.u[q] = cvt_pk_bf16(vb.x, vb.y);
        }
#pragma unroll
        for (int nt = 0; nt < 4; nt++) {
            s16x8 bf0 = wbfB[((tap * 2 + 0) * 4 + nt) * 64 + l];
            s16x8 bf1 = wbfB[((tap * 2 + 1) * 4 + nt) * 64 + l];
            acc[nt] = __builtin_amdgcn_mfma_f32_16x16x32_bf16(A0.v, bf0, acc[nt], 0, 0, 0);
            acc[nt] = __builtin_amdgcn_mfma_f32_16x16x32_bf16(A1.v, bf1, acc[nt], 0, 0, 0);
        }
    }

    float* ob = out + (size_t)b * O_ * HW;
    int gp0 = pw + csub * 4;
#pragma unroll
    for (int nt = 0; nt < 4; nt++) {
        int oc = nt * 16 + pl;
        *(f32x4*)(ob + (size_t)oc * HW + gp0) = acc[nt];
    }
}

extern "C" void kernel_launch(void* const* d_in, const int* in_sizes, int n_in,
                              void* d_out, int out_size, void* d_ws, size_t ws_size,
                              hipStream_t stream) {
    const float* x    = (const float*)d_in[0];
    const float* offw = (const float*)d_in[1];
    const float* offb = (const float*)d_in[2];
    const float* modw = (const float*)d_in[3];
    const float* modb = (const float*)d_in[4];
    const float* w    = (const float*)d_in[5];
    float* out = (float*)d_out;
    float* ws  = (float*)d_ws;

    prep_weights<<<dim3(216), dim3(256), 0, stream>>>(offw, modw, w, ws);
    transpose_x<<<dim3(HW / 64, B_), dim3(256), 0, stream>>>(x, ws);
    fused<<<dim3(64, 8), dim3(1024), 0, stream>>>(ws, offb, modb, out);
}

// Round 20
// 69.015 us; speedup vs baseline: 1.6310x; 1.3020x over previous
//
#include <hip/hip_runtime.h>
#include <math.h>

#define B_ 8
#define C_ 64
#define H_ 128
#define W_ 128
#define O_ 64
#define HW (H_*W_)

typedef float f32x4 __attribute__((ext_vector_type(4)));
typedef float f32x2 __attribute__((ext_vector_type(2)));
typedef short s16x8 __attribute__((ext_vector_type(8)));

// ws layout (float offsets)
#define XT_BUF   0              // NHWC bf16 x: 8*16384*64 us = 4194304 f
#define WBFA_BUF 4194304        // conv B-frags: 18432 us = 9216 f
#define WBFB_BUF 4203520        // deform B-frags: 36864 us = 18432 f

__device__ __forceinline__ unsigned short f2bf(float f) {
    union { float f; unsigned u; } v; v.f = f;
    unsigned r = (v.u + 0x7FFFu + ((v.u >> 16) & 1u)) >> 16;  // RNE
    return (unsigned short)r;
}
__device__ __forceinline__ unsigned cvt_pk_bf16(float lo, float hi) {
    unsigned r;
    asm("v_cvt_pk_bf16_f32 %0, %1, %2" : "=v"(r) : "v"(lo), "v"(hi));
    return r;
}
// u32 reg i of an s16x8 holds bf16 channels (2i) in low 16 and (2i+1) in high 16.
__device__ __forceinline__ f32x2 bfpair(s16x8 v, int i) {
    union { s16x8 s; unsigned u[4]; } c; c.s = v;
    unsigned r = c.u[i];
    union { unsigned u; float f; } lo, hi;
    lo.u = r << 16;
    hi.u = r & 0xFFFF0000u;
    f32x2 out; out.x = lo.f; out.y = hi.f;
    return out;
}
// async global->LDS, 16B per lane: LDS dst = wave-uniform base + lane*16.
__device__ __forceinline__ void gload_lds16(const void* g, void* l) {
    __builtin_amdgcn_global_load_lds(
        (const __attribute__((address_space(1))) unsigned int*)g,
        (__attribute__((address_space(3))) unsigned int*)l, 16, 0, 0);
}

// B-fragments (bf16) for mfma_f32_16x16x32_bf16:
//  B[k=c][n=oc], lane l holds c = ks*32 + (l>>4)*8 + j, oc = nt*16 + (l&15).
__global__ void prep_weights(const float* __restrict__ offw,
                             const float* __restrict__ modw,
                             const float* __restrict__ w,
                             float* __restrict__ ws) {
    int t = blockIdx.x * 256 + threadIdx.x;
    unsigned short* wbfA = (unsigned short*)(ws + WBFA_BUF);
    unsigned short* wbfB = (unsigned short*)(ws + WBFB_BUF);
    if (t < 18432) {
        int j = t & 7, lane = (t >> 3) & 63, nt = (t >> 9) & 1, ks = (t >> 10) & 1, tap = t >> 11;
        int c = ks * 32 + ((lane >> 4) & 3) * 8 + j;
        int oc = nt * 16 + (lane & 15);
        float v = 0.f;
        if (oc < 18)      v = offw[oc * (C_ * 9) + c * 9 + tap];
        else if (oc < 27) v = modw[(oc - 18) * (C_ * 9) + c * 9 + tap];
        wbfA[t] = f2bf(v);
    } else {
        int t2 = t - 18432;
        if (t2 < 36864) {
            int j = t2 & 7, lane = (t2 >> 3) & 63, nt = (t2 >> 9) & 3, ks = (t2 >> 11) & 1, tap = t2 >> 12;
            int c = ks * 32 + ((lane >> 4) & 3) * 8 + j;
            int o = nt * 16 + (lane & 15);
            wbfB[t2] = f2bf(w[o * (C_ * 9) + c * 9 + tap]);
        }
    }
}

// x NCHW fp32 -> x_t NHWC bf16 (rows of 64 ch = 128B). NT reads (read-once).
__global__ __launch_bounds__(256) void transpose_x(const float* __restrict__ x,
                                                   float* __restrict__ ws) {
    __shared__ float lds[64 * 65];
    int b = blockIdx.x & 7;
    int chunk = (blockIdx.y << 5) | (blockIdx.x >> 3);   // 0..255
    int p0 = chunk * 64;
    int t = threadIdx.x;
    int pl = t & 63;
    const float* xb = x + (size_t)b * C_ * HW + p0;
#pragma unroll
    for (int i = 0; i < 16; i++) {
        int c = (t >> 6) + i * 4;
        lds[c * 65 + pl] = __builtin_nontemporal_load(&xb[(size_t)c * HW + pl]);
    }
    __syncthreads();
    unsigned short* xo = (unsigned short*)(ws + XT_BUF) + ((size_t)b * HW + p0) * 64;
#pragma unroll
    for (int pass = 0; pass < 2; pass++) {
        int p = (t >> 3) + pass * 32;
        int c0 = (t & 7) * 8;
        union { unsigned short u[8]; s16x8 v; } pk;
#pragma unroll
        for (int j = 0; j < 8; j++) pk.u[j] = f2bf(lds[(c0 + j) * 65 + p]);
        *(s16x8*)(xo + (size_t)p * 64 + c0) = pk.v;
    }
}

// ---- FUSED conv+deform: both phases gather from a 27x27 LDS x-tile; ----
// ---- deform weights nt=0,1 staged in LDS (single-pass tap loop).      ----
// LDS: 93312 (tile) + 18432 + 9216 + 36864 (w-half) = 157824 B.
__global__ __launch_bounds__(1024) void fused(const float* __restrict__ ws,
                                              const float* __restrict__ offb,
                                              const float* __restrict__ modb,
                                              float* __restrict__ out) {
    __shared__ s16x8 xtile_v[5832];      // 93312 B: 729 px * 128B, swizzled
    __shared__ float offL[16][18][16];   // [wave][oc][px]
    __shared__ float mskL[16][9][16];
    __shared__ char wlds[36864];         // deform B-frags, nt=0,1: [tk18][nt2][1024B]
    char* xtile = (char*)xtile_v;
    int t = threadIdx.x;
    int wv = t >> 6, l = t & 63;
    int b = blockIdx.x & 7;
    int tile = (blockIdx.y << 3) | (blockIdx.x >> 3);    // 0..63
    int ty = tile >> 3, tx = tile & 7;
    int t0y = ty * 16, t0x = tx * 16;
    int y = t0y + wv, x0 = t0x;
    int pw = y * W_ + x0;
    int pl = l & 15, csub = l >> 4;

    const unsigned short* xtb = (const unsigned short*)(ws + XT_BUF) + (size_t)b * HW * 64;
    const s16x8* wbfA = (const s16x8*)(ws + WBFA_BUF);
    const s16x8* wbfB = (const s16x8*)(ws + WBFB_BUF);
    const char* wsrcB = (const char*)(ws + WBFB_BUF);

    // stage deform weight half (nt=0,1): 36 chunks of 1KB across 16 waves
#pragma unroll
    for (int i = 0; i < 3; i++) {
        int ch = wv + i * 16;
        if (ch < 36) {
            int tk = ch >> 1, ntl = ch & 1;
            gload_lds16(wsrcB + (size_t)(tk * 4 + ntl) * 1024 + l * 16, wlds + ch * 1024);
        }
    }
    // stage x-tile: 27x27 px * 8 chunks of 16B, XOR-swizzled (chunk ^= p&7)
#pragma unroll
    for (int k = 0; k < 6; k++) {
        int i = t + k * 1024;
        if (i < 5832) {
            int p = i >> 3, w8 = i & 7;
            int r = p / 27, cc = p - r * 27;
            int gr = min(max(t0y - 5 + r, 0), H_ - 1);
            int gc = min(max(t0x - 5 + cc, 0), W_ - 1);
            s16x8 v = *(const s16x8*)(xtb + (size_t)((gr << 7) + gc) * 64 + (w8 << 3));
            *(s16x8*)(xtile + p * 128 + ((w8 ^ (p & 7)) << 4)) = v;
        }
    }
    __syncthreads();   // tile + weight-half staged (drains vmcnt + ds_writes)

    // ================= phase 1: conv (gathers from LDS tile) =================
    {
        int oc0 = pl, oc1 = 16 + pl;
        float bi0 = offb[oc0];
        float bi1 = (oc1 < 18) ? offb[oc1] : (oc1 < 27 ? modb[oc1 - 18] : 0.f);
        f32x4 acc0 = {bi0, bi0, bi0, bi0};
        f32x4 acc1 = {bi1, bi1, bi1, bi1};
        const s16x8 zf = {0, 0, 0, 0, 0, 0, 0, 0};

        for (int tap = 0; tap < 9; tap++) {
            int ys = y + tap / 3 - 1;
            int xs = x0 + pl + tap % 3 - 1;
            bool vld = ((unsigned)ys < (unsigned)H_) && ((unsigned)xs < (unsigned)W_);
            int yc = min(max(ys, 0), H_ - 1);
            int xc = min(max(xs, 0), W_ - 1);
            int sp = (yc - t0y + 5) * 27 + (xc - t0x + 5);   // always in [0,729)
            s16x8 a0 = *(const s16x8*)(xtile + sp * 128 + ((csub ^ (sp & 7)) << 4));
            s16x8 a1 = *(const s16x8*)(xtile + sp * 128 + (((4 + csub) ^ (sp & 7)) << 4));
            a0 = vld ? a0 : zf;
            a1 = vld ? a1 : zf;
            s16x8 b00 = wbfA[((tap * 2 + 0) * 2 + 0) * 64 + l];
            s16x8 b01 = wbfA[((tap * 2 + 0) * 2 + 1) * 64 + l];
            s16x8 b10 = wbfA[((tap * 2 + 1) * 2 + 0) * 64 + l];
            s16x8 b11 = wbfA[((tap * 2 + 1) * 2 + 1) * 64 + l];
            acc0 = __builtin_amdgcn_mfma_f32_16x16x32_bf16(a0, b00, acc0, 0, 0, 0);
            acc1 = __builtin_amdgcn_mfma_f32_16x16x32_bf16(a0, b01, acc1, 0, 0, 0);
            acc0 = __builtin_amdgcn_mfma_f32_16x16x32_bf16(a1, b10, acc0, 0, 0, 0);
            acc1 = __builtin_amdgcn_mfma_f32_16x16x32_bf16(a1, b11, acc1, 0, 0, 0);
        }

        // epilogue -> LDS (D row = pixel csub*4+j, col = oc)
#pragma unroll
        for (int j = 0; j < 4; j++)
            offL[wv][oc0][csub * 4 + j] = fminf(fmaxf(acc0[j], -32.f), 32.f);
        if (oc1 < 18) {
#pragma unroll
            for (int j = 0; j < 4; j++)
                offL[wv][oc1][csub * 4 + j] = fminf(fmaxf(acc1[j], -32.f), 32.f);
        } else if (oc1 < 27) {
#pragma unroll
            for (int j = 0; j < 4; j++)
                mskL[wv][oc1 - 18][csub * 4 + j] = 2.f / (1.f + __expf(-acc1[j]));
        }
    }
    __syncthreads();   // publishes offL/mskL

    // ================= phase 2: deform (verbatim round-19 body, ==============
    // ================= weights nt<2 from LDS, nt>=2 from global) =============
    int xx = x0 + pl;
    const unsigned short* xtb2 = xtb + csub * 8;

    float dyv[9], dxv[9], mmv[9];
#pragma unroll
    for (int tap = 0; tap < 9; tap++) {
        dyv[tap] = offL[wv][2 * tap][pl];
        dxv[tap] = offL[wv][2 * tap + 1][pl];
        mmv[tap] = mskL[wv][tap][pl];
    }

    f32x4 acc[4];
#pragma unroll
    for (int nt = 0; nt < 4; nt++) acc[nt] = (f32x4)0.f;

#pragma unroll
    for (int tap = 0; tap < 9; tap++) {
        float py = (float)(y + tap / 3 - 1) + dyv[tap];
        float px = (float)(xx + tap % 3 - 1) + dxv[tap];
        float mm = mmv[tap];
        float fy = floorf(py), fx = floorf(px);
        int y0 = (int)fy, xq = (int)fx;
        float wy = py - fy, wx = px - fx;
        bool vy0 = (unsigned)y0 < (unsigned)H_;
        bool vy1 = (unsigned)(y0 + 1) < (unsigned)H_;
        bool vx0 = (unsigned)xq < (unsigned)W_;
        bool vx1 = (unsigned)(xq + 1) < (unsigned)W_;
        int yc0 = min(max(y0, 0), H_ - 1), yc1 = min(max(y0 + 1, 0), H_ - 1);
        int xc0 = min(max(xq, 0), W_ - 1), xc1 = min(max(xq + 1, 0), W_ - 1);
        float e0 = (1.f - wy) * (1.f - wx) * mm * ((vy0 && vx0) ? 1.f : 0.f);
        float e1 = (1.f - wy) * wx         * mm * ((vy0 && vx1) ? 1.f : 0.f);
        float e2 = wy * (1.f - wx)         * mm * ((vy1 && vx0) ? 1.f : 0.f);
        float e3 = wy * wx                 * mm * ((vy1 && vx1) ? 1.f : 0.f);

        int sy0 = yc0 - t0y + 5, sy1 = yc1 - t0y + 5;
        int sx0 = xc0 - t0x + 5, sx1 = xc1 - t0x + 5;
        bool inb = ((unsigned)sy0 < 27u) && ((unsigned)sy1 < 27u) &&
                   ((unsigned)sx0 < 27u) && ((unsigned)sx1 < 27u);
        int cy0 = min(max(sy0, 0), 26), cy1 = min(max(sy1, 0), 26);
        int cx0 = min(max(sx0, 0), 26), cx1 = min(max(sx1, 0), 26);
        int q00 = cy0 * 27 + cx0, q01 = cy0 * 27 + cx1;
        int q10 = cy1 * 27 + cx0, q11 = cy1 * 27 + cx1;

        s16x8 g00a = *(const s16x8*)(xtile + q00 * 128 + ((csub ^ (q00 & 7)) << 4));
        s16x8 g00b = *(const s16x8*)(xtile + q00 * 128 + (((4 + csub) ^ (q00 & 7)) << 4));
        s16x8 g01a = *(const s16x8*)(xtile + q01 * 128 + ((csub ^ (q01 & 7)) << 4));
        s16x8 g01b = *(const s16x8*)(xtile + q01 * 128 + (((4 + csub) ^ (q01 & 7)) << 4));
        s16x8 g10a = *(const s16x8*)(xtile + q10 * 128 + ((csub ^ (q10 & 7)) << 4));
        s16x8 g10b = *(const s16x8*)(xtile + q10 * 128 + (((4 + csub) ^ (q10 & 7)) << 4));
        s16x8 g11a = *(const s16x8*)(xtile + q11 * 128 + ((csub ^ (q11 & 7)) << 4));
        s16x8 g11b = *(const s16x8*)(xtile + q11 * 128 + (((4 + csub) ^ (q11 & 7)) << 4));

        if (!inb) {   // rare per-lane fixup: far offsets gather from global
            const unsigned short* p00 = xtb2 + (size_t)(yc0 * W_ + xc0) * 64;
            const unsigned short* p01 = xtb2 + (size_t)(yc0 * W_ + xc1) * 64;
            const unsigned short* p10 = xtb2 + (size_t)(yc1 * W_ + xc0) * 64;
            const unsigned short* p11 = xtb2 + (size_t)(yc1 * W_ + xc1) * 64;
            g00a = *(const s16x8*)p00; g00b = *(const s16x8*)(p00 + 32);
            g01a = *(const s16x8*)p01; g01b = *(const s16x8*)(p01 + 32);
            g10a = *(const s16x8*)p10; g10b = *(const s16x8*)(p10 + 32);
            g11a = *(const s16x8*)p11; g11b = *(const s16x8*)(p11 + 32);
        }

        f32x2 e0v = {e0, e0}, e1v = {e1, e1}, e2v = {e2, e2}, e3v = {e3, e3};
        union { unsigned u[4]; s16x8 v; } A0, A1;
#pragma unroll
        for (int q = 0; q < 4; q++) {
            f32x2 va = e0v * bfpair(g00a, q) + e1v * bfpair(g01a, q)
                     + e2v * bfpair(g10a, q) + e3v * bfpair(g11a, q);
            A0.u[q] = cvt_pk_bf16(va.x, va.y);
            f32x2 vb = e0v * bfpair(g00b, q) + e1v * bfpair(g01b, q)
                     + e2v * bfpair(g10b, q) + e3v * bfpair(g11b, q);
            A1.u[q] = cvt_pk_bf16(vb.x, vb.y);
        }
#pragma unroll
        for (int nt = 0; nt < 4; nt++) {
            s16x8 bf0, bf1;
            if (nt < 2) {   // static (unrolled): LDS half
                bf0 = *(const s16x8*)(wlds + ((tap * 2 + 0) * 2 + nt) * 1024 + l * 16);
                bf1 = *(const s16x8*)(wlds + ((tap * 2 + 1) * 2 + nt) * 1024 + l * 16);
            } else {        // global half
                bf0 = wbfB[((tap * 2 + 0) * 4 + nt) * 64 + l];
                bf1 = wbfB[((tap * 2 + 1) * 4 + nt) * 64 + l];
            }
            acc[nt] = __builtin_amdgcn_mfma_f32_16x16x32_bf16(A0.v, bf0, acc[nt], 0, 0, 0);
            acc[nt] = __builtin_amdgcn_mfma_f32_16x16x32_bf16(A1.v, bf1, acc[nt], 0, 0, 0);
        }
    }

    float* ob = out + (size_t)b * O_ * HW;
    int gp0 = pw + csub * 4;
#pragma unroll
    for (int nt = 0; nt < 4; nt++) {
        int oc = nt * 16 + pl;
        *(f32x4*)(ob + (size_t)oc * HW + gp0) = acc[nt];
    }
}

extern "C" void kernel_launch(void* const* d_in, const int* in_sizes, int n_in,
                              void* d_out, int out_size, void* d_ws, size_t ws_size,
                              hipStream_t stream) {
    const float* x    = (const float*)d_in[0];
    const float* offw = (const float*)d_in[1];
    const float* offb = (const float*)d_in[2];
    const float* modw = (const float*)d_in[3];
    const float* modb = (const float*)d_in[4];
    const float* w    = (const float*)d_in[5];
    float* out = (float*)d_out;
    float* ws  = (float*)d_ws;

    prep_weights<<<dim3(216), dim3(256), 0, stream>>>(offw, modw, w, ws);
    transpose_x<<<dim3(HW / 64, B_), dim3(256), 0, stream>>>(x, ws);
    fused<<<dim3(64, 8), dim3(1024), 0, stream>>>(ws, offb, modb, out);
}

// Round 21
// 64.366 us; speedup vs baseline: 1.7488x; 1.0722x over previous
//
#include <hip/hip_runtime.h>
#include <math.h>

#define B_ 8
#define C_ 64
#define H_ 128
#define W_ 128
#define O_ 64
#define HW (H_*W_)

// tile geometry: 16x16 pixels + halo 3 each side -> 22x22
#define HALO 3
#define TDIM 22
#define TPX  (TDIM*TDIM)   // 484

typedef float f32x4 __attribute__((ext_vector_type(4)));
typedef float f32x2 __attribute__((ext_vector_type(2)));
typedef short s16x8 __attribute__((ext_vector_type(8)));

// ws layout (float offsets)
#define XT_BUF   0              // NHWC bf16 x: 8*16384*64 us = 4194304 f
#define WBFA_BUF 4194304        // conv B-frags: 18432 us = 9216 f
#define WBFB_BUF 4203520        // deform B-frags: 36864 us = 18432 f

__device__ __forceinline__ unsigned short f2bf(float f) {
    union { float f; unsigned u; } v; v.f = f;
    unsigned r = (v.u + 0x7FFFu + ((v.u >> 16) & 1u)) >> 16;  // RNE
    return (unsigned short)r;
}
__device__ __forceinline__ unsigned cvt_pk_bf16(float lo, float hi) {
    unsigned r;
    asm("v_cvt_pk_bf16_f32 %0, %1, %2" : "=v"(r) : "v"(lo), "v"(hi));
    return r;
}
// u32 reg i of an s16x8 holds bf16 channels (2i) in low 16 and (2i+1) in high 16.
__device__ __forceinline__ f32x2 bfpair(s16x8 v, int i) {
    union { s16x8 s; unsigned u[4]; } c; c.s = v;
    unsigned r = c.u[i];
    union { unsigned u; float f; } lo, hi;
    lo.u = r << 16;
    hi.u = r & 0xFFFF0000u;
    f32x2 out; out.x = lo.f; out.y = hi.f;
    return out;
}
// async global->LDS, 16B per lane: LDS dst = wave-uniform base + lane*16.
__device__ __forceinline__ void gload_lds16(const void* g, void* l) {
    __builtin_amdgcn_global_load_lds(
        (const __attribute__((address_space(1))) unsigned int*)g,
        (__attribute__((address_space(3))) unsigned int*)l, 16, 0, 0);
}

// B-fragments (bf16) for mfma_f32_16x16x32_bf16:
//  B[k=c][n=oc], lane l holds c = ks*32 + (l>>4)*8 + j, oc = nt*16 + (l&15).
__global__ void prep_weights(const float* __restrict__ offw,
                             const float* __restrict__ modw,
                             const float* __restrict__ w,
                             float* __restrict__ ws) {
    int t = blockIdx.x * 256 + threadIdx.x;
    unsigned short* wbfA = (unsigned short*)(ws + WBFA_BUF);
    unsigned short* wbfB = (unsigned short*)(ws + WBFB_BUF);
    if (t < 18432) {
        int j = t & 7, lane = (t >> 3) & 63, nt = (t >> 9) & 1, ks = (t >> 10) & 1, tap = t >> 11;
        int c = ks * 32 + ((lane >> 4) & 3) * 8 + j;
        int oc = nt * 16 + (lane & 15);
        float v = 0.f;
        if (oc < 18)      v = offw[oc * (C_ * 9) + c * 9 + tap];
        else if (oc < 27) v = modw[(oc - 18) * (C_ * 9) + c * 9 + tap];
        wbfA[t] = f2bf(v);
    } else {
        int t2 = t - 18432;
        if (t2 < 36864) {
            int j = t2 & 7, lane = (t2 >> 3) & 63, nt = (t2 >> 9) & 3, ks = (t2 >> 11) & 1, tap = t2 >> 12;
            int c = ks * 32 + ((lane >> 4) & 3) * 8 + j;
            int o = nt * 16 + (lane & 15);
            wbfB[t2] = f2bf(w[o * (C_ * 9) + c * 9 + tap]);
        }
    }
}

// x NCHW fp32 -> x_t NHWC bf16 (rows of 64 ch = 128B). NT reads (read-once).
__global__ __launch_bounds__(256) void transpose_x(const float* __restrict__ x,
                                                   float* __restrict__ ws) {
    __shared__ float lds[64 * 65];
    int b = blockIdx.x & 7;
    int chunk = (blockIdx.y << 5) | (blockIdx.x >> 3);   // 0..255
    int p0 = chunk * 64;
    int t = threadIdx.x;
    int pl = t & 63;
    const float* xb = x + (size_t)b * C_ * HW + p0;
#pragma unroll
    for (int i = 0; i < 16; i++) {
        int c = (t >> 6) + i * 4;
        lds[c * 65 + pl] = __builtin_nontemporal_load(&xb[(size_t)c * HW + pl]);
    }
    __syncthreads();
    unsigned short* xo = (unsigned short*)(ws + XT_BUF) + ((size_t)b * HW + p0) * 64;
#pragma unroll
    for (int pass = 0; pass < 2; pass++) {
        int p = (t >> 3) + pass * 32;
        int c0 = (t & 7) * 8;
        union { unsigned short u[8]; s16x8 v; } pk;
#pragma unroll
        for (int j = 0; j < 8; j++) pk.u[j] = f2bf(lds[(c0 + j) * 65 + p]);
        *(s16x8*)(xo + (size_t)p * 64 + c0) = pk.v;
    }
}

// ---- FUSED conv+deform: 22x22 LDS x-tile (halo 3), ALL deform weights in
// ---- LDS, no conv->deform barrier (offL/mskL are wave-private).
// LDS: 61952 (tile) + 18432 + 9216 + 73728 (wlds) = 163328 B (<= 160 KB).
__global__ __launch_bounds__(1024) void fused(const float* __restrict__ ws,
                                              const float* __restrict__ offb,
                                              const float* __restrict__ modb,
                                              float* __restrict__ out) {
    __shared__ s16x8 xtile_v[TPX * 8];   // 61952 B: 484 px * 128B, swizzled
    __shared__ float offL[16][18][16];   // [wave][oc][px]  (wave-private)
    __shared__ float mskL[16][9][16];
    __shared__ char wlds[73728];         // deform B-frags: [tap2ks 18][nt 4][1024B]
    char* xtile = (char*)xtile_v;
    int t = threadIdx.x;
    int wv = t >> 6, l = t & 63;
    int b = blockIdx.x & 7;
    int tile = (blockIdx.y << 3) | (blockIdx.x >> 3);    // 0..63
    int ty = tile >> 3, tx = tile & 7;
    int t0y = ty * 16, t0x = tx * 16;
    int y = t0y + wv, x0 = t0x;
    int pw = y * W_ + x0;
    int pl = l & 15, csub = l >> 4;

    const unsigned short* xtb = (const unsigned short*)(ws + XT_BUF) + (size_t)b * HW * 64;
    const s16x8* wbfA = (const s16x8*)(ws + WBFA_BUF);
    const char* wsrcB = (const char*)(ws + WBFB_BUF);

    // stage ALL deform weights: 72 chunks of 1KB across 16 waves (1:1 layout)
#pragma unroll
    for (int i = 0; i < 5; i++) {
        int ch = wv + i * 16;
        if (ch < 72)
            gload_lds16(wsrcB + (size_t)ch * 1024 + l * 16, wlds + ch * 1024);
    }
    // stage x-tile: 22x22 px * 8 chunks of 16B, XOR-swizzled (chunk ^= p&7)
#pragma unroll
    for (int k = 0; k < 4; k++) {
        int i = t + k * 1024;
        if (i < TPX * 8) {
            int p = i >> 3, w8 = i & 7;
            int r = p / TDIM, cc = p - r * TDIM;
            int gr = min(max(t0y - HALO + r, 0), H_ - 1);
            int gc = min(max(t0x - HALO + cc, 0), W_ - 1);
            s16x8 v = *(const s16x8*)(xtb + (size_t)((gr << 7) + gc) * 64 + (w8 << 3));
            *(s16x8*)(xtile + p * 128 + ((w8 ^ (p & 7)) << 4)) = v;
        }
    }
    __syncthreads();   // tile + weights staged (drains vmcnt + ds_writes)

    // ================= phase 1: conv (gathers from LDS tile) =================
    {
        int oc0 = pl, oc1 = 16 + pl;
        float bi0 = offb[oc0];
        float bi1 = (oc1 < 18) ? offb[oc1] : (oc1 < 27 ? modb[oc1 - 18] : 0.f);
        f32x4 acc0 = {bi0, bi0, bi0, bi0};
        f32x4 acc1 = {bi1, bi1, bi1, bi1};
        const s16x8 zf = {0, 0, 0, 0, 0, 0, 0, 0};

        for (int tap = 0; tap < 9; tap++) {
            int ys = y + tap / 3 - 1;
            int xs = x0 + pl + tap % 3 - 1;
            bool vld = ((unsigned)ys < (unsigned)H_) && ((unsigned)xs < (unsigned)W_);
            int yc = min(max(ys, 0), H_ - 1);
            int xc = min(max(xs, 0), W_ - 1);
            int sp = (yc - t0y + HALO) * TDIM + (xc - t0x + HALO);  // in [0,TPX)
            s16x8 a0 = *(const s16x8*)(xtile + sp * 128 + ((csub ^ (sp & 7)) << 4));
            s16x8 a1 = *(const s16x8*)(xtile + sp * 128 + (((4 + csub) ^ (sp & 7)) << 4));
            a0 = vld ? a0 : zf;
            a1 = vld ? a1 : zf;
            s16x8 b00 = wbfA[((tap * 2 + 0) * 2 + 0) * 64 + l];
            s16x8 b01 = wbfA[((tap * 2 + 0) * 2 + 1) * 64 + l];
            s16x8 b10 = wbfA[((tap * 2 + 1) * 2 + 0) * 64 + l];
            s16x8 b11 = wbfA[((tap * 2 + 1) * 2 + 1) * 64 + l];
            acc0 = __builtin_amdgcn_mfma_f32_16x16x32_bf16(a0, b00, acc0, 0, 0, 0);
            acc1 = __builtin_amdgcn_mfma_f32_16x16x32_bf16(a0, b01, acc1, 0, 0, 0);
            acc0 = __builtin_amdgcn_mfma_f32_16x16x32_bf16(a1, b10, acc0, 0, 0, 0);
            acc1 = __builtin_amdgcn_mfma_f32_16x16x32_bf16(a1, b11, acc1, 0, 0, 0);
        }

        // epilogue -> LDS (wave-private slice; no block barrier needed)
#pragma unroll
        for (int j = 0; j < 4; j++)
            offL[wv][oc0][csub * 4 + j] = fminf(fmaxf(acc0[j], -32.f), 32.f);
        if (oc1 < 18) {
#pragma unroll
            for (int j = 0; j < 4; j++)
                offL[wv][oc1][csub * 4 + j] = fminf(fmaxf(acc1[j], -32.f), 32.f);
        } else if (oc1 < 27) {
#pragma unroll
            for (int j = 0; j < 4; j++)
                mskL[wv][oc1 - 18][csub * 4 + j] = 2.f / (1.f + __expf(-acc1[j]));
        }
    }
    // NO __syncthreads: offL/mskL[wv] written and read by the same wave only;
    // compiler-inserted lgkmcnt orders the same-wave LDS RAW.

    // ================= phase 2: deform (LDS tile + LDS weights) ==============
    int xx = x0 + pl;
    const unsigned short* xtb2 = xtb + csub * 8;

    float dyv[9], dxv[9], mmv[9];
#pragma unroll
    for (int tap = 0; tap < 9; tap++) {
        dyv[tap] = offL[wv][2 * tap][pl];
        dxv[tap] = offL[wv][2 * tap + 1][pl];
        mmv[tap] = mskL[wv][tap][pl];
    }

    f32x4 acc[4];
#pragma unroll
    for (int nt = 0; nt < 4; nt++) acc[nt] = (f32x4)0.f;

#pragma unroll
    for (int tap = 0; tap < 9; tap++) {
        float py = (float)(y + tap / 3 - 1) + dyv[tap];
        float px = (float)(xx + tap % 3 - 1) + dxv[tap];
        float mm = mmv[tap];
        float fy = floorf(py), fx = floorf(px);
        int y0 = (int)fy, xq = (int)fx;
        float wy = py - fy, wx = px - fx;
        bool vy0 = (unsigned)y0 < (unsigned)H_;
        bool vy1 = (unsigned)(y0 + 1) < (unsigned)H_;
        bool vx0 = (unsigned)xq < (unsigned)W_;
        bool vx1 = (unsigned)(xq + 1) < (unsigned)W_;
        int yc0 = min(max(y0, 0), H_ - 1), yc1 = min(max(y0 + 1, 0), H_ - 1);
        int xc0 = min(max(xq, 0), W_ - 1), xc1 = min(max(xq + 1, 0), W_ - 1);
        float e0 = (1.f - wy) * (1.f - wx) * mm * ((vy0 && vx0) ? 1.f : 0.f);
        float e1 = (1.f - wy) * wx         * mm * ((vy0 && vx1) ? 1.f : 0.f);
        float e2 = wy * (1.f - wx)         * mm * ((vy1 && vx0) ? 1.f : 0.f);
        float e3 = wy * wx                 * mm * ((vy1 && vx1) ? 1.f : 0.f);

        int sy0 = yc0 - t0y + HALO, sy1 = yc1 - t0y + HALO;
        int sx0 = xc0 - t0x + HALO, sx1 = xc1 - t0x + HALO;
        bool inb = ((unsigned)sy0 < (unsigned)TDIM) && ((unsigned)sy1 < (unsigned)TDIM) &&
                   ((unsigned)sx0 < (unsigned)TDIM) && ((unsigned)sx1 < (unsigned)TDIM);
        int cy0 = min(max(sy0, 0), TDIM - 1), cy1 = min(max(sy1, 0), TDIM - 1);
        int cx0 = min(max(sx0, 0), TDIM - 1), cx1 = min(max(sx1, 0), TDIM - 1);
        int q00 = cy0 * TDIM + cx0, q01 = cy0 * TDIM + cx1;
        int q10 = cy1 * TDIM + cx0, q11 = cy1 * TDIM + cx1;

        s16x8 g00a = *(const s16x8*)(xtile + q00 * 128 + ((csub ^ (q00 & 7)) << 4));
        s16x8 g00b = *(const s16x8*)(xtile + q00 * 128 + (((4 + csub) ^ (q00 & 7)) << 4));
        s16x8 g01a = *(const s16x8*)(xtile + q01 * 128 + ((csub ^ (q01 & 7)) << 4));
        s16x8 g01b = *(const s16x8*)(xtile + q01 * 128 + (((4 + csub) ^ (q01 & 7)) << 4));
        s16x8 g10a = *(const s16x8*)(xtile + q10 * 128 + ((csub ^ (q10 & 7)) << 4));
        s16x8 g10b = *(const s16x8*)(xtile + q10 * 128 + (((4 + csub) ^ (q10 & 7)) << 4));
        s16x8 g11a = *(const s16x8*)(xtile + q11 * 128 + ((csub ^ (q11 & 7)) << 4));
        s16x8 g11b = *(const s16x8*)(xtile + q11 * 128 + (((4 + csub) ^ (q11 & 7)) << 4));

        if (!inb) {   // per-lane fixup (~3-4%): far offsets gather from global
            const unsigned short* p00 = xtb2 + (size_t)(yc0 * W_ + xc0) * 64;
            const unsigned short* p01 = xtb2 + (size_t)(yc0 * W_ + xc1) * 64;
            const unsigned short* p10 = xtb2 + (size_t)(yc1 * W_ + xc0) * 64;
            const unsigned short* p11 = xtb2 + (size_t)(yc1 * W_ + xc1) * 64;
            g00a = *(const s16x8*)p00; g00b = *(const s16x8*)(p00 + 32);
            g01a = *(const s16x8*)p01; g01b = *(const s16x8*)(p01 + 32);
            g10a = *(const s16x8*)p10; g10b = *(const s16x8*)(p10 + 32);
            g11a = *(const s16x8*)p11; g11b = *(const s16x8*)(p11 + 32);
        }

        f32x2 e0v = {e0, e0}, e1v = {e1, e1}, e2v = {e2, e2}, e3v = {e3, e3};
        union { unsigned u[4]; s16x8 v; } A0, A1;
#pragma unroll
        for (int q = 0; q < 4; q++) {
            f32x2 va = e0v * bfpair(g00a, q) + e1v * bfpair(g01a, q)
                     + e2v * bfpair(g10a, q) + e3v * bfpair(g11a, q);
            A0.u[q] = cvt_pk_bf16(va.x, va.y);
            f32x2 vb = e0v * bfpair(g00b, q) + e1v * bfpair(g01b, q)
                     + e2v * bfpair(g10b, q) + e3v * bfpair(g11b, q);
            A1.u[q] = cvt_pk_bf16(vb.x, vb.y);
        }
#pragma unroll
        for (int nt = 0; nt < 4; nt++) {
            s16x8 bf0 = *(const s16x8*)(wlds + ((tap * 2 + 0) * 4 + nt) * 1024 + l * 16);
            s16x8 bf1 = *(const s16x8*)(wlds + ((tap * 2 + 1) * 4 + nt) * 1024 + l * 16);
            acc[nt] = __builtin_amdgcn_mfma_f32_16x16x32_bf16(A0.v, bf0, acc[nt], 0, 0, 0);
            acc[nt] = __builtin_amdgcn_mfma_f32_16x16x32_bf16(A1.v, bf1, acc[nt], 0, 0, 0);
        }
    }

    float* ob = out + (size_t)b * O_ * HW;
    int gp0 = pw + csub * 4;
#pragma unroll
    for (int nt = 0; nt < 4; nt++) {
        int oc = nt * 16 + pl;
        *(f32x4*)(ob + (size_t)oc * HW + gp0) = acc[nt];
    }
}

extern "C" void kernel_launch(void* const* d_in, const int* in_sizes, int n_in,
                              void* d_out, int out_size, void* d_ws, size_t ws_size,
                              hipStream_t stream) {
    const float* x    = (const float*)d_in[0];
    const float* offw = (const float*)d_in[1];
    const float* offb = (const float*)d_in[2];
    const float* modw = (const float*)d_in[3];
    const float* modb = (const float*)d_in[4];
    const float* w    = (const float*)d_in[5];
    float* out = (float*)d_out;
    float* ws  = (float*)d_ws;

    prep_weights<<<dim3(216), dim3(256), 0, stream>>>(offw, modw, w, ws);
    transpose_x<<<dim3(HW / 64, B_), dim3(256), 0, stream>>>(x, ws);
    fused<<<dim3(64, 8), dim3(1024), 0, stream>>>(ws, offb, modb, out);
}